// Round 11
// baseline (347.403 us; speedup 1.0000x reference)
//
#include <hip/hip_runtime.h>

#define NA 51
#define TPB 256
#define RPW 16            // rows per wave (4 lanes collaborate on one row)
#define RPB 64            // rows per block (4 waves)
#define KCLAMP 52

// 4B-aligned vectors for per-lane global loads (bases are only 4B-aligned)
typedef float v4u __attribute__((ext_vector_type(4), aligned(4)));
typedef float v2u __attribute__((ext_vector_type(2), aligned(4)));
// 16B-aligned vector for LDS reads / coalesced global stores
typedef float v4a __attribute__((ext_vector_type(4), aligned(16)));

// C51 Bellman projection, QUAD-LANE rows: lane q in [0,4) of a row computes
// atoms [13q, 13q+12] (12 atoms for q=3). s = reward*2.5, k = floor(s)
// clamped to +/-52 (equivalent), f = frac(s):
//   out[i] = (1-f)*p[i-k]*[0<=i-k<=50] + f*p[i-k-1]*[...] + (i==0)*m_lo + (i==50)*m_hi
//
// Round-11 change (single variable vs r10): NONTEMPORAL copy-out stores.
// Rationale: steady-state, L3 (256 MB) is contended by probs (204 MB, re-read
// each iter) and the output write-allocate stream (204 MB) — measured FETCH
// ~102 MB = half of probs = eviction by write allocation. nt stores on the
// copy-out (full 64B lines: each wave stores 3264 contiguous aligned bytes)
// should keep output from allocating, leaving probs L3-resident. Supporting
// A/B: r6(nt)=162us vs r7(plain)=175us, same kernel — nt was 8% faster with
// LOWER fetch+write. Write amplification only ever appeared with PERSISTENT
// grids (non-persistent WRITE_SIZE is bit-exact 199218.75 KB every run).
__global__ __launch_bounds__(TPB, 8) void c51_bellman_kernel(
    const float* __restrict__ reward,
    const float* __restrict__ probs,
    float* __restrict__ out,
    int bs)
{
    __shared__ __align__(16) float lds[4][RPW * NA];   // 4 waves x 3264 B = 13056 B
    const int tid  = threadIdx.x;
    const int lane = tid & 63;
    const int wv   = tid >> 6;
    const int q    = lane & 3;          // slot within the row's quad
    const int lr   = lane >> 2;         // local row within the wave
    const int wrow0 = blockIdx.x * RPB + wv * RPW;
    const int r     = wrow0 + lr;
    const bool edge = (blockIdx.x == 0) | (blockIdx.x == (int)gridDim.x - 1);

    float* const wlds = lds[wv];
    const int a0    = 13 * q;               // first atom of my slice
    const int count = (q < 3) ? 13 : 12;    // atoms in my slice

    if (r < bs) {
        const float s  = reward[r] * 2.5f;  // r / 0.4 (same addr across quad)
        const float kf = floorf(s);
        const float f  = s - kf;
        int k = (int)kf;
        k = min(max(k, -KCLAMP), KCLAMP);   // out-of-range k: all terms zero anyway
        const float* rp = probs + (size_t)r * NA;

        // ---- my row slice -> regs (always in-row; q=3 pads with 0) ----
        float row[13];
        *(v4u*)&row[0] = *(const v4u*)&rp[a0];
        *(v4u*)&row[4] = *(const v4u*)&rp[a0 + 4];
        *(v4u*)&row[8] = *(const v4u*)&rp[a0 + 8];
        row[12] = (q < 3) ? rp[a0 + 12] : 0.0f;

        // ---- gather window w[m] = p[a0 + m - k - 1], m in [0,14) ----
        // Strays at most 212 B before / ~420 B after the row: unsafe only for
        // rows {0,1} and {bs-2,bs-1} -> first/last BLOCK (uniform branch)
        // clamps per element into the row (no-op clamp for masked-in slots).
        float w[14];
        if (!edge) {
            const float* wb = rp + a0 - k - 1;
            *(v4u*)&w[0]  = *(const v4u*)&wb[0];
            *(v4u*)&w[4]  = *(const v4u*)&wb[4];
            *(v4u*)&w[8]  = *(const v4u*)&wb[8];
            *(v2u*)&w[12] = *(const v2u*)&wb[12];
        } else {
            #pragma unroll
            for (int m = 0; m < 14; ++m)
                w[m] = rp[min(max(a0 + m - k - 1, 0), NA - 1)];
        }

        // ---- clamp masses: partial over my slice, then quad-reduce ----
        float m_lo = 0.0f, m_hi = 0.0f;
        #pragma unroll
        for (int c = 0; c < 13; ++c) {
            const float t = (float)(a0 + c) + s;   // q=3,c=12: row[12]=0, harmless
            if (t < 0.0f)  m_lo += row[c];
            if (t > 50.0f) m_hi += row[c];
        }
        m_lo += __shfl_xor(m_lo, 1, 64); m_lo += __shfl_xor(m_lo, 2, 64);
        m_hi += __shfl_xor(m_hi, 1, 64); m_hi += __shfl_xor(m_hi, 2, 64);

        // ---- projection: w[c] = p[i-k-1], w[c+1] = p[i-k] for i = a0+c ----
        //   i==0  (q0,c0):  o = (1-f)*cur + m_lo            (w2=0 at i=0)
        //   i==50 (q3,c11): o = (f==0 ? cur : f*prev) + m_hi
        //   else:           o = (1-f)*cur + f*prev
        const float w1 = 1.0f - f;
        float* wp = wlds + lr * NA + a0;
        #pragma unroll
        for (int c = 0; c < 13; ++c) {
            const int i = a0 + c;
            const float pl = ((unsigned)(i - k - 1) <= 50u) ? w[c]     : 0.0f;
            const float cu = ((unsigned)(i - k)     <= 50u) ? w[c + 1] : 0.0f;
            float o;
            if (i == 0)           o = w1 * cu + m_lo;
            else if (i == NA - 1) o = ((f == 0.0f) ? cu : f * pl) + m_hi;
            else                  o = w1 * cu + f * pl;
            if (c < count) wp[c] = o;   // q=3,c=12 would alias next row's atom 0
        }
    }

    // ---- copy-out: wave-private LDS -> coalesced NONTEMPORAL 16B stores ----
    // (no barrier: a wave's DS ops execute in order, so reads see its writes;
    //  each wave's store range = 3264 contiguous aligned bytes = 51 full 64B
    //  lines -> nt cannot cause partial-line amplification)
    const int nrw   = min(RPW, max(0, bs - wrow0));
    const int nelem = nrw * NA;                       // 816 floats when full
    const int n4    = nelem >> 2;
    const v4a* l4 = (const v4a*)wlds;                 // wave base 3264B-aligned
    v4a* o4 = (v4a*)(out + (size_t)wrow0 * NA);       // wrow0*51*4 % 16 == 0
    for (int e = lane; e < n4; e += 64)
        __builtin_nontemporal_store(l4[e], o4 + e);
    for (int e = (n4 << 2) + lane; e < nelem; e += 64)
        __builtin_nontemporal_store(wlds[e], out + (size_t)wrow0 * NA + e);
}

extern "C" void kernel_launch(void* const* d_in, const int* in_sizes, int n_in,
                              void* d_out, int out_size, void* d_ws, size_t ws_size,
                              hipStream_t stream) {
    const float* reward = (const float*)d_in[0];
    const float* probs  = (const float*)d_in[1];
    // d_in[2] = atom_values: unused — atom j sits exactly at index j in idx-space
    float* out = (float*)d_out;
    const int bs = in_sizes[0];

    const int blocks = (bs + RPB - 1) / RPB;
    c51_bellman_kernel<<<blocks, TPB, 0, stream>>>(reward, probs, out, bs);
}

// Round 12
// 343.156 us; speedup vs baseline: 1.0124x; 1.0124x over previous
//
#include <hip/hip_runtime.h>

#define NA 51
#define TPB 256
#define RPW 16                  // rows per wave (4 lanes collaborate on one row)
#define RPB 64                  // rows per block (4 waves)
#define WNF (RPW * NA)          // 816 floats = 3264 B per wave block
#define GUARD 56                // LDS guard floats each side (k clamped to +/-52)
#define KCLAMP 52

// 16B-aligned vector for LDS reads / coalesced global stores
typedef float v4a __attribute__((ext_vector_type(4), aligned(16)));

// vmcnt(0) drain + scheduler fence (rule #18)
#define WAITV0 do { asm volatile("s_waitcnt vmcnt(0)" ::: "memory"); \
                    __builtin_amdgcn_sched_barrier(0); } while (0)

// C51 Bellman projection: coalesced global_load_lds input staging + quad-lane
// compute + window gathered FROM LDS (probs read from global exactly once).
//   s = reward*2.5, k = floor(s) clamped to +/-52 (equivalent), f = frac(s)
//   out[i] = (1-f)*p[i-k]*[0<=i-k<=50] + f*p[i-k-1]*[...] + (i==0)*m_lo + (i==50)*m_hi
//
// Why this combination (r12): r10/r11 read probs TWICE via per-lane divergent
// vectors (64 distinct 64B lines per instr ~= 64 L1-tag lookups) ~ 650
// lookups/16-row tile ~ 66 us/CU serialized — plateau-sized. r2 had coalesced
// input but 64-row waves (long chains, 12 waves/CU). Here: 4 glds instrs
// stage a wave's 16 rows (51 lines, ~16 lookups/KB), the gather window comes
// from LDS (no 2nd global read), quad-lane compute keeps chains short and
// VGPRs ~50 -> high occupancy, everything wave-private (NO barriers).
// Guarded LDS (+/-56 floats) makes out-of-row window reads safe garbage that
// the atom-index masks discard — the block-edge special case disappears.
// Stores plain (r11: nt null), LDS->global coalesced b128 (r3: lane-major
// stores = 4.6x write amplification).
__global__ __launch_bounds__(TPB, 8) void c51_bellman_kernel(
    const float* __restrict__ reward,
    const float* __restrict__ probs,
    float* __restrict__ out,
    int bs)
{
    __shared__ __align__(16) float lds[GUARD + 4 * WNF + GUARD];  // 13504 B
    const int tid  = threadIdx.x;
    const int lane = tid & 63;
    const int wv   = tid >> 6;
    const int q    = lane & 3;          // slot within the row's quad
    const int lr   = lane >> 2;         // local row within the wave
    const int wrow0 = blockIdx.x * RPB + wv * RPW;

    float* const wb = lds + GUARD + wv * WNF;   // wave block; GUARD*4=224B -> 16B-aligned
    const int nrw  = min(RPW, max(0, bs - wrow0));
    const bool full = (nrw == RPW);

    // ---- stage this wave's 16 rows (3264 B) into LDS, coalesced DMA ----
    if (full) {
        const char* src = (const char*)(probs + (size_t)wrow0 * NA);
        #pragma unroll
        for (int c = 0; c < 3; ++c) {
            __builtin_amdgcn_global_load_lds(
                (const __attribute__((address_space(1))) void*)
                    (unsigned long long)(src + c * 1024 + lane * 16),
                (__attribute__((address_space(3))) void*)
                    (unsigned long long)(wb + c * 256),
                16, 0, 0);
        }
        if (lane < 12) {    // tail 192 B, exec-masked, wave-uniform LDS base
            __builtin_amdgcn_global_load_lds(
                (const __attribute__((address_space(1))) void*)
                    (unsigned long long)(src + 3072 + lane * 16),
                (__attribute__((address_space(3))) void*)
                    (unsigned long long)(wb + 768),
                16, 0, 0);
        }
    } else if (nrw > 0) {   // ragged tail wave (not hit at bs=1e6): scalar stage
        const int ne = nrw * NA;
        for (int e = lane; e < ne; e += 64)
            wb[e] = probs[(size_t)wrow0 * NA + e];
    }

    float s = 0.0f;
    if (lr < nrw) s = reward[wrow0 + lr] * 2.5f;   // quad-shared addr (1 line/16 rows)
    WAITV0;   // wave-private staging: waitcnt only, no barrier anywhere

    // ---- quad-lane compute: lane q owns atoms [13q, 13q+12] (12 for q=3) ----
    if (lr < nrw) {
        const float kf = floorf(s);
        const float f  = s - kf;
        int k = (int)kf;
        k = min(max(k, -KCLAMP), KCLAMP);   // out-of-range k: all terms zero anyway
        float* const rp = wb + lr * NA;     // own row in LDS
        const int a0    = 13 * q;
        const int count = (q < 3) ? 13 : 12;

        // my row slice (for clamp masses); q=3 pads slot 12 with 0
        float row[13];
        #pragma unroll
        for (int c = 0; c < 12; ++c) row[c] = rp[a0 + c];
        row[12] = (q < 3) ? rp[a0 + 12] : 0.0f;

        float m_lo = 0.0f, m_hi = 0.0f;
        #pragma unroll
        for (int c = 0; c < 13; ++c) {
            const float t = (float)(a0 + c) + s;
            if (t < 0.0f)  m_lo += row[c];
            if (t > 50.0f) m_hi += row[c];
        }
        m_lo += __shfl_xor(m_lo, 1, 64); m_lo += __shfl_xor(m_lo, 2, 64);
        m_hi += __shfl_xor(m_hi, 1, 64); m_hi += __shfl_xor(m_hi, 2, 64);

        // gather window from LDS: w[m] = p_flat[lr*51 + a0 + m - k - 1].
        // Strays <=53 floats outside the row -> lands in neighbor rows or the
        // array guards: in-bounds garbage, discarded by the atom-index masks.
        float w[14];
        const float* wsrc = rp + a0 - k - 1;
        #pragma unroll
        for (int m = 0; m < 14; ++m) w[m] = wsrc[m];

        // projection; in-place write of my slice. Per-lane may-alias (runtime k)
        // forces the compiler to keep ALL window reads before the writes, and a
        // wave's DS ops execute in lockstep program order -> cross-lane safe
        // (same argument as r2's verified in-place pass).
        const float w1 = 1.0f - f;
        float* wp = rp + a0;
        #pragma unroll
        for (int c = 0; c < 13; ++c) {
            const int i = a0 + c;
            const float pl = ((unsigned)(i - k - 1) <= 50u) ? w[c]     : 0.0f;
            const float cu = ((unsigned)(i - k)     <= 50u) ? w[c + 1] : 0.0f;
            float o;
            if (i == 0)           o = w1 * cu + m_lo;
            else if (i == NA - 1) o = ((f == 0.0f) ? cu : f * pl) + m_hi;
            else                  o = w1 * cu + f * pl;
            if (c < count) wp[c] = o;   // q=3,c=12 would alias next row's atom 0
        }
    }

    // ---- copy-out: wave-private LDS -> coalesced 16B plain stores ----
    // (no barrier: a wave's DS ops execute in order, reads see its writes)
    const int ne = nrw * NA;                    // 816 floats when full
    const int n4 = ne >> 2;
    const v4a* l4 = (const v4a*)wb;
    v4a* o4 = (v4a*)(out + (size_t)wrow0 * NA); // wrow0*204 % 16 == 0
    for (int e = lane; e < n4; e += 64) o4[e] = l4[e];
    for (int e = (n4 << 2) + lane; e < ne; e += 64)
        out[(size_t)wrow0 * NA + e] = wb[e];
}

extern "C" void kernel_launch(void* const* d_in, const int* in_sizes, int n_in,
                              void* d_out, int out_size, void* d_ws, size_t ws_size,
                              hipStream_t stream) {
    const float* reward = (const float*)d_in[0];
    const float* probs  = (const float*)d_in[1];
    // d_in[2] = atom_values: unused — atom j sits exactly at index j in idx-space
    float* out = (float*)d_out;
    const int bs = in_sizes[0];

    const int blocks = (bs + RPB - 1) / RPB;
    c51_bellman_kernel<<<blocks, TPB, 0, stream>>>(reward, probs, out, bs);
}